// Round 1
// baseline (155.402 us; speedup 1.0000x reference)
//
#include <hip/hip_runtime.h>
#include <hip/hip_bf16.h>

#define SELF_D 36
#define ENT_D  28
#define HID    256
#define OBS    1688   // 36 + 28*59
#define NE     59     // 20 opp + 19 par + 20 noisy
#define RPB    4      // rows per block-iteration

// ws float layout
#define WS_A     0        // 36*256
#define WS_B     9216     // 28*256
#define WS_C     16384    // 256
#define WS_MSEL  16640    // 108  (36 x 3)
#define WS_MENT  16748    // 252  (3 x 28 x 3)
#define WS_CG    17000    // 3
#define WS_WATT  17008    // 28
#define WS_TOTAL 17040

__global__ __launch_bounds__(256)
void setup_kernel(const float* __restrict__ Watt, const float* __restrict__ We,
                  const float* __restrict__ be,  const float* __restrict__ Wse,
                  const float* __restrict__ bse, const float* __restrict__ Wg,
                  const float* __restrict__ bg,  const float* __restrict__ Wo,
                  const float* __restrict__ bo,  float* __restrict__ ws) {
  const int blk = blockIdx.x;
  const int c = threadIdx.x;
  if (blk < 36) {
    // A[k][c] = sum_r We[k][r]*Wo[r][c] + sum_r (Wse[k][r]+Wse[36+k][r])*Wo[256+r][c]
    int k = blk;
    float acc = 0.f;
    for (int r = 0; r < 256; ++r) acc += We[k*256 + r] * Wo[r*256 + c];
    for (int r = 0; r < 256; ++r) acc += (Wse[k*256 + r] + Wse[(36+k)*256 + r]) * Wo[(256+r)*256 + c];
    ws[WS_A + k*256 + c] = acc;
  } else if (blk < 64) {
    // Bm[k][c] = sum_r We[36+k][r]*Wo[r][c]
    int k = blk - 36;
    float acc = 0.f;
    for (int r = 0; r < 256; ++r) acc += We[(36+k)*256 + r] * Wo[r*256 + c];
    ws[WS_B + k*256 + c] = acc;
  } else if (blk == 64) {
    // cvec[c] = be@Wo_top + bse@Wo_bot + bo
    float acc = bo[c];
    for (int r = 0; r < 256; ++r) acc += be[r] * Wo[r*256 + c];
    for (int r = 0; r < 256; ++r) acc += bse[r] * Wo[(256+r)*256 + c];
    ws[WS_C + c] = acc;
  } else {
    // small derived tensors; 391 tasks over 256 threads
    for (int t = c; t < 391; t += 256) {
      if (t < 108) {
        int k = t / 3, j = t - 3*k;
        float acc = 0.f;
        for (int r = 0; r < 256; ++r) {
          float wg = Wg[r*3 + j] + Wg[(256+r)*3 + j] + Wg[(512+r)*3 + j];
          acc += We[k*256 + r] * wg;
        }
        ws[WS_MSEL + t] = acc;
      } else if (t < 360) {
        int idx = t - 108;
        int g = idx / 84, rem = idx - 84*g;
        int k = rem / 3, j = rem - 3*k;
        float acc = 0.f;
        for (int r = 0; r < 256; ++r) acc += We[(36+k)*256 + r] * Wg[(256*g + r)*3 + j];
        ws[WS_MENT + idx] = acc;
      } else if (t < 363) {
        int j = t - 360;
        float acc = bg[j];
        for (int r = 0; r < 256; ++r)
          acc += be[r] * (Wg[r*3 + j] + Wg[(256+r)*3 + j] + Wg[(512+r)*3 + j]);
        ws[WS_CG + j] = acc;
      } else {
        int k = t - 363;
        ws[WS_WATT + k] = Watt[36 + k];   // entity part of Watt only
      }
    }
  }
}

__global__ __launch_bounds__(256)
void main_kernel(const float* __restrict__ x, const float* __restrict__ ws,
                 float* __restrict__ out, int B) {
  __shared__ float rows[RPB][OBS];
  __shared__ float slog[RPB][64];
  __shared__ float satt[RPB][64];
  __shared__ float sebar[RPB][84];
  __shared__ float se2[RPB][28];
  __shared__ float slg[RPB][4];
  __shared__ float sW[28];
  __shared__ float sMsel[108];
  __shared__ float sMent[252];
  __shared__ float scg[4];

  const int tid = threadIdx.x;

  // one-time per-block loads of small derived tensors
  for (int t = tid; t < 28;  t += 256) sW[t]    = ws[WS_WATT + t];
  for (int t = tid; t < 108; t += 256) sMsel[t] = ws[WS_MSEL + t];
  for (int t = tid; t < 252; t += 256) sMent[t] = ws[WS_MENT + t];
  if (tid < 3) scg[tid] = ws[WS_CG + tid];

  // A/B columns held in registers: thread `tid` owns output column c=tid
  float Areg[36], Breg[28];
#pragma unroll
  for (int k = 0; k < 36; ++k) Areg[k] = ws[WS_A + k*256 + tid];
#pragma unroll
  for (int k = 0; k < 28; ++k) Breg[k] = ws[WS_B + k*256 + tid];
  const float cc = ws[WS_C + tid];

  const int ngroups = B / RPB;
  for (int grp = blockIdx.x; grp < ngroups; grp += gridDim.x) {
    const int row0 = grp * RPB;

    // Phase A: stage 4 contiguous rows (6752 floats = 1688 float4)
    {
      const float4* src = (const float4*)(x + (size_t)row0 * OBS);
      float4* dst = (float4*)&rows[0][0];
#pragma unroll
      for (int i = 0; i < 7; ++i) {
        int idx = tid + i * 256;
        if (idx < (RPB * OBS) / 4) dst[idx] = src[idx];
      }
    }
    __syncthreads();

    // Phase B: entity attention logits (wave w handles row w; lane i -> entity i)
    {
      int r = tid >> 6, i = tid & 63;
      if (i < NE) {
        const float* e = &rows[r][SELF_D + ENT_D * i];
        float acc = 0.f;
#pragma unroll
        for (int k = 0; k < ENT_D; ++k) acc += e[k] * sW[k];
        slog[r][i] = acc;
      }
    }
    __syncthreads();

    // Phase C: per-group softmax -> att weights (12 threads, serial over <=20)
    if (tid < RPB * 3) {
      const int gbase[3] = {0, 20, 39};
      const int gcnt[3]  = {20, 19, 20};
      int r = tid / 3, g = tid - 3*r;
      int base = gbase[g], cnt = gcnt[g];
      float m = -1e30f;
      for (int i = 0; i < cnt; ++i) m = fmaxf(m, slog[r][base + i]);
      float s = 0.f;
      for (int i = 0; i < cnt; ++i) s += __expf(slog[r][base + i] - m);
      float inv = 1.f / s;
      for (int i = 0; i < cnt; ++i) satt[r][base + i] = __expf(slog[r][base + i] - m) * inv;
    }
    __syncthreads();

    // Phase D: attention-weighted entity means, ebar[r][g][k]
    for (int task = tid; task < RPB * 84; task += 256) {
      const int gbase[3] = {0, 20, 39};
      const int gcnt[3]  = {20, 19, 20};
      int r = task / 84, m2 = task - 84*r;
      int g = m2 / 28, k = m2 - 28*g;
      int base = gbase[g], cnt = gcnt[g];
      float acc = 0.f;
      for (int i = 0; i < cnt; ++i)
        acc += satt[r][base + i] * rows[r][SELF_D + ENT_D*(base + i) + k];
      sebar[r][m2] = acc;
    }
    __syncthreads();

    // Phase E: gate logits (12 threads)
    if (tid < RPB * 3) {
      int r = tid / 3, j = tid - 3*r;
      float acc = scg[j];
#pragma unroll
      for (int k = 0; k < 36; ++k) acc += rows[r][k] * sMsel[k*3 + j];
      for (int m = 0; m < 84; ++m) acc += sebar[r][m] * sMent[m*3 + j];
      slg[r][j] = acc;
    }
    __syncthreads();

    // Phase F: gate softmax + gated entity mix ē[k]
    for (int task = tid; task < RPB * 28; task += 256) {
      int r = task / 28, k = task - 28*r;
      float l0 = slg[r][0], l1 = slg[r][1], l2 = slg[r][2];
      float m = fmaxf(l0, fmaxf(l1, l2));
      float e0 = __expf(l0 - m), e1 = __expf(l1 - m), e2 = __expf(l2 - m);
      float inv = 1.f / (e0 + e1 + e2);
      se2[r][k] = (e0 * sebar[r][k] + e1 * sebar[r][28 + k] + e2 * sebar[r][56 + k]) * inv;
    }
    __syncthreads();

    // Phase G: out[row][c] = cc + self@A[:,c] + ē@Bm[:,c]   (A/B in registers)
    {
      float* o = out + (size_t)row0 * HID + tid;
#pragma unroll
      for (int r = 0; r < RPB; ++r) {
        float acc = cc;
#pragma unroll
        for (int k = 0; k < 36; ++k) acc += rows[r][k] * Areg[k];
#pragma unroll
        for (int k = 0; k < 28; ++k) acc += se2[r][k] * Breg[k];
        o[(size_t)r * HID] = acc;
      }
    }
    __syncthreads();  // protect rows/scratch before next iteration
  }
}

extern "C" void kernel_launch(void* const* d_in, const int* in_sizes, int n_in,
                              void* d_out, int out_size, void* d_ws, size_t ws_size,
                              hipStream_t stream) {
  const float* x    = (const float*)d_in[0];
  const float* Watt = (const float*)d_in[1];
  const float* We   = (const float*)d_in[3];
  const float* be   = (const float*)d_in[4];
  const float* Wse  = (const float*)d_in[5];
  const float* bse  = (const float*)d_in[6];
  const float* Wg   = (const float*)d_in[7];
  const float* bg   = (const float*)d_in[8];
  const float* Wo   = (const float*)d_in[9];
  const float* bo   = (const float*)d_in[10];
  float* out = (float*)d_out;
  float* ws  = (float*)d_ws;
  const int B = in_sizes[0] / OBS;

  setup_kernel<<<66, 256, 0, stream>>>(Watt, We, be, Wse, bse, Wg, bg, Wo, bo, ws);
  main_kernel<<<2048, 256, 0, stream>>>(x, ws, out, B);
}